// Round 1
// baseline (3163.954 us; speedup 1.0000x reference)
//
#include <hip/hip_runtime.h>
#include <math.h>

#define NSTEPS 100
#define BATCHN 4096

typedef __attribute__((ext_vector_type(8))) short bf16x8;   // 8 x bf16 (4 VGPRs)
typedef __attribute__((ext_vector_type(4))) float f32x4;

#define MFMA16(a, b, c) __builtin_amdgcn_mfma_f32_16x16x32_bf16(a, b, c, 0, 0, 0)

__device__ __forceinline__ unsigned short rne_bf16(float x) {
    unsigned u = __float_as_uint(x);
    return (unsigned short)((u + 0x7FFFu + ((u >> 16) & 1u)) >> 16);
}
__device__ __forceinline__ float bf16_f(unsigned short h) {
    return __uint_as_float(((unsigned)h) << 16);
}
__device__ __forceinline__ float gelu_f(float x) {
    float x3 = x * x * x;
    float e = __expf(-1.5957691216057308f * (x + 0.044715f * x3));
    return x / (1.0f + e);
}

// ---------------------------------------------------------------------------
// Prep: swizzle W1/W2/W3 (fp32) into bf16 hi/lo B-fragment layout in ws.
// (unchanged from verified kernel)
// ---------------------------------------------------------------------------
__global__ __launch_bounds__(256) void prep_weights(
    const float* __restrict__ W1, const float* __restrict__ W2,
    const float* __restrict__ W3, short* __restrict__ ws)
{
    int g = blockIdx.x * 256 + threadIdx.x;
    if (g >= 272 * 64) return;
    int fp = g >> 6, l = g & 63;
    int m = l & 15, kq = (l >> 4) * 8;
    const float* W; int ndim, kdim, nt, kt;
    if (fp < 80)       { W = W1; ndim = 256; kdim = 129; nt = fp / 5;          kt = fp % 5; }
    else if (fp < 208) { W = W2; ndim = 256; kdim = 256; nt = (fp - 80) >> 3;  kt = (fp - 80) & 7; }
    else               { W = W3; ndim = 128; kdim = 256; nt = (fp - 208) >> 3; kt = (fp - 208) & 7; }
    int n = nt * 16 + m;
    bf16x8 vh, vl;
    #pragma unroll
    for (int j = 0; j < 8; ++j) {
        int k = kt * 32 + kq + j;
        float v = (k < kdim) ? W[k * ndim + n] : 0.f;
        unsigned short h = rne_bf16(v);
        float r = v - bf16_f(h);
        vh[j] = (short)h;
        vl[j] = (short)rne_bf16(r);
    }
    short* base = ws + (size_t)fp * 1024 + l * 8;
    *(bf16x8*)base = vh;
    *(bf16x8*)(base + 512) = vl;
}

// ---------------------------------------------------------------------------
// Main persistent kernel: 256 blocks x 1024 threads (16 waves), 16 rows/block,
// 100 steps. Changes vs prior version:
//  - W1 register-resident (reloaded for next step during current step's tail)
//  - W2/W3 batched prefetch issued right after the previous phase's MFMAs
//  - noise prefetched into regs at phase-1 start, consumed in update
//  - phase-3 split-K removed (waves 0-7 full K); p3 buffer + 2 barriers gone
//  - fp32 master state xm moved from LDS into 4 regs/lane
//  - a1/a2 reduce moved to top of next step (overlaps phase 1)
// ---------------------------------------------------------------------------
__global__ __launch_bounds__(1024) void sde_mfma_kernel(
    const float* __restrict__ noise,
    const float* __restrict__ b1, const float* __restrict__ b2,
    const float* __restrict__ b3, const short* __restrict__ ws,
    float* __restrict__ out)
{
    __shared__ short xa [5 * 2 * 512];   // x,t A-frags (K=160), hi/lo
    __shared__ short h1a[8 * 2 * 512];   // h1 (K=256)
    __shared__ short h2a[8 * 2 * 512];   // h2 (K=256)
    __shared__ float part[8 * 16 * 2];   // per-wave row partials (udw, uu)

    const int tid  = threadIdx.x;
    const int w    = tid >> 6;          // wave 0..15
    const int l    = tid & 63;          // lane
    const int m16  = l & 15;
    const int q    = l >> 4;            // quad
    const int row0 = blockIdx.x * 16;

    // init
    for (int i = tid; i < 5 * 2 * 512; i += 1024) xa[i] = 0;
    {   // traj[0] rows for this block (x=0, a1=a2=0)
        float* t0 = out + (size_t)row0 * 130;
        for (int i = tid; i < 16 * 130; i += 1024) t0[i] = 0.f;
    }
    if (blockIdx.x == 0 && tid <= NSTEPS)
        out[(size_t)(NSTEPS + 1) * BATCHN * 130 + tid] = (float)tid * 0.01f;

    float a1 = 0.f, a2 = 0.f;                 // live in tid<16 threads
    const float bias1 = b1[w * 16 + m16];
    const float bias2 = b2[w * 16 + m16];
    const float bias3 = b3[(w & 7) * 16 + m16];

    // persistent W1 fragments (40 VGPRs)
    bf16x8 w1h[5], w1l[5];
    #pragma unroll
    for (int kt = 0; kt < 5; ++kt) {
        const short* bp = ws + (size_t)(w * 5 + kt) * 1024 + l * 8;
        w1h[kt] = *(const bf16x8*)bp;
        w1l[kt] = *(const bf16x8*)(bp + 512);
    }

    float xreg[4] = {0.f, 0.f, 0.f, 0.f};     // fp32 master state (w<8)
    float nzv[4];                              // prefetched noise (w<8)

    __syncthreads();

    for (int step = 0; step < NSTEPS; ++step) {
        const float tn   = (float)(step + 1) * 0.01f;
        const float tc   = (float)step * 0.01f;
        const float dt   = tn - tc;
        const float sqdt = sqrtf(dt);

        // ---- finish PREVIOUS step's a1/a2 (overlaps phase 1; race-safe:
        //      part's next writers must pass barriers #1,#2 first) ----
        if (step > 0 && tid < 16) {
            float sudw = 0.f, suu = 0.f;
            #pragma unroll
            for (int wv = 0; wv < 8; ++wv) {
                sudw += part[(wv * 16 + tid) * 2 + 0];
                suu  += part[(wv * 16 + tid) * 2 + 1];
            }
            float tp  = (float)(step - 1) * 0.01f;
            float dtp = tc - tp;
            a1 += sudw;                        // gamma = 1
            a2 = fmaf(suu * 0.5f, dtp, a2);
            float* tro = out + ((size_t)step * BATCHN + row0 + tid) * 130;
            tro[128] = a1;
            tro[129] = a2;
        }

        // ---- noise prefetch for THIS step (consumed in update) ----
        if (w < 8) {
            const float* nz = noise + ((size_t)step * BATCHN + row0) * 128 + (w * 16 + m16);
            #pragma unroll
            for (int r = 0; r < 4; ++r)
                nzv[r] = __builtin_nontemporal_load(&nz[(q * 4 + r) * 128]);
        }

        // ---- phase 1: h1 = gelu([x,t] @ W1 + b1), nt = w, K-tiles 5 ----
        {
            f32x4 accA = {0.f, 0.f, 0.f, 0.f};
            f32x4 accB = {0.f, 0.f, 0.f, 0.f};
            #pragma unroll
            for (int kt = 0; kt < 5; ++kt) {
                bf16x8 ah = *(const bf16x8*)&xa[(kt * 2 + 0) * 512 + l * 8];
                bf16x8 al = *(const bf16x8*)&xa[(kt * 2 + 1) * 512 + l * 8];
                if (kt & 1) {
                    accB = MFMA16(ah, w1h[kt], accB);
                    accB = MFMA16(al, w1h[kt], accB);
                    accB = MFMA16(ah, w1l[kt], accB);
                } else {
                    accA = MFMA16(ah, w1h[kt], accA);
                    accA = MFMA16(al, w1h[kt], accA);
                    accA = MFMA16(ah, w1l[kt], accA);
                }
            }
            f32x4 acc = accA + accB;

            // prefetch W2 (64 VGPRs in flight; W1 now dead)
            bf16x8 w2h[8], w2l[8];
            #pragma unroll
            for (int kt = 0; kt < 8; ++kt) {
                const short* bp = ws + (size_t)(80 + w * 8 + kt) * 1024 + l * 8;
                w2h[kt] = *(const bf16x8*)bp;
                w2l[kt] = *(const bf16x8*)(bp + 512);
            }

            // epilogue 1
            {
                const int ktw   = w >> 1;
                const int gbase = ((w & 1) * 2 + (m16 >> 3)) * 16;
                const int jj    = m16 & 7;
                #pragma unroll
                for (int r = 0; r < 4; ++r) {
                    float h = gelu_f(acc[r] + bias1);
                    unsigned short hh = rne_bf16(h);
                    unsigned short hl = rne_bf16(h - bf16_f(hh));
                    int lp = gbase + q * 4 + r;
                    h1a[(ktw * 2 + 0) * 512 + lp * 8 + jj] = (short)hh;
                    h1a[(ktw * 2 + 1) * 512 + lp * 8 + jj] = (short)hl;
                }
            }
            __syncthreads();   // barrier #1

            // ---- phase 2: h2 = gelu(h1 @ W2 + b2), nt = w, K-tiles 8 ----
            f32x4 acc2A = {0.f, 0.f, 0.f, 0.f};
            f32x4 acc2B = {0.f, 0.f, 0.f, 0.f};
            #pragma unroll
            for (int kt = 0; kt < 8; ++kt) {
                bf16x8 ah = *(const bf16x8*)&h1a[(kt * 2 + 0) * 512 + l * 8];
                bf16x8 al = *(const bf16x8*)&h1a[(kt * 2 + 1) * 512 + l * 8];
                if (kt & 1) {
                    acc2B = MFMA16(ah, w2h[kt], acc2B);
                    acc2B = MFMA16(al, w2h[kt], acc2B);
                    acc2B = MFMA16(ah, w2l[kt], acc2B);
                } else {
                    acc2A = MFMA16(ah, w2h[kt], acc2A);
                    acc2A = MFMA16(al, w2h[kt], acc2A);
                    acc2A = MFMA16(ah, w2l[kt], acc2A);
                }
            }
            f32x4 acc2 = acc2A + acc2B;

            // prefetch W3 (w<8) or reload next-step W1 (w>=8)
            bf16x8 w3h[8], w3l[8];
            if (w < 8) {
                #pragma unroll
                for (int kt = 0; kt < 8; ++kt) {
                    const short* bp = ws + (size_t)(208 + w * 8 + kt) * 1024 + l * 8;
                    w3h[kt] = *(const bf16x8*)bp;
                    w3l[kt] = *(const bf16x8*)(bp + 512);
                }
            } else {
                #pragma unroll
                for (int kt = 0; kt < 5; ++kt) {
                    const short* bp = ws + (size_t)(w * 5 + kt) * 1024 + l * 8;
                    w1h[kt] = *(const bf16x8*)bp;
                    w1l[kt] = *(const bf16x8*)(bp + 512);
                }
            }

            // epilogue 2
            {
                const int ktw   = w >> 1;
                const int gbase = ((w & 1) * 2 + (m16 >> 3)) * 16;
                const int jj    = m16 & 7;
                #pragma unroll
                for (int r = 0; r < 4; ++r) {
                    float h = gelu_f(acc2[r] + bias2);
                    unsigned short hh = rne_bf16(h);
                    unsigned short hl = rne_bf16(h - bf16_f(hh));
                    int lp = gbase + q * 4 + r;
                    h2a[(ktw * 2 + 0) * 512 + lp * 8 + jj] = (short)hh;
                    h2a[(ktw * 2 + 1) * 512 + lp * 8 + jj] = (short)hl;
                }
            }
            __syncthreads();   // barrier #2

            // ---- phase 3 (full K) + update, waves 0-7 only ----
            if (w < 8) {
                f32x4 a3A = {0.f, 0.f, 0.f, 0.f};
                f32x4 a3B = {0.f, 0.f, 0.f, 0.f};
                #pragma unroll
                for (int kt = 0; kt < 8; ++kt) {
                    bf16x8 ah = *(const bf16x8*)&h2a[(kt * 2 + 0) * 512 + l * 8];
                    bf16x8 al = *(const bf16x8*)&h2a[(kt * 2 + 1) * 512 + l * 8];
                    if (kt & 1) {
                        a3B = MFMA16(ah, w3h[kt], a3B);
                        a3B = MFMA16(al, w3h[kt], a3B);
                        a3B = MFMA16(ah, w3l[kt], a3B);
                    } else {
                        a3A = MFMA16(ah, w3h[kt], a3A);
                        a3A = MFMA16(al, w3h[kt], a3A);
                        a3A = MFMA16(ah, w3l[kt], a3A);
                    }
                }
                f32x4 acc3 = a3A + a3B;

                // reload next-step W1 (W3 now dead)
                #pragma unroll
                for (int kt = 0; kt < 5; ++kt) {
                    const short* bp = ws + (size_t)(w * 5 + kt) * 1024 + l * 8;
                    w1h[kt] = *(const bf16x8*)bp;
                    w1l[kt] = *(const bf16x8*)(bp + 512);
                }

                // update: x += u*dt + dW; partial sums; refresh xa
                const int c = w * 16 + m16;
                float* tro = out + ((size_t)(step + 1) * BATCHN + row0) * 130;
                const int ktx = c >> 5;
                const int lpb = ((c & 31) >> 3) * 16;
                const int jx  = c & 7;
                #pragma unroll
                for (int r = 0; r < 4; ++r) {
                    int row = q * 4 + r;
                    float u  = acc3[r] + bias3;
                    float dW = sqdt * nzv[r];
                    float xn = fmaf(u, dt, xreg[r]) + dW;
                    xreg[r] = xn;
                    __builtin_nontemporal_store(xn, &tro[row * 130 + c]);
                    unsigned short xh = rne_bf16(xn);
                    unsigned short xl = rne_bf16(xn - bf16_f(xh));
                    int lp = lpb + row;
                    xa[(ktx * 2 + 0) * 512 + lp * 8 + jx] = (short)xh;
                    xa[(ktx * 2 + 1) * 512 + lp * 8 + jx] = (short)xl;
                    float udw = u * dW, uu = u * u;
                    udw += __shfl_xor(udw, 1);  uu += __shfl_xor(uu, 1);
                    udw += __shfl_xor(udw, 2);  uu += __shfl_xor(uu, 2);
                    udw += __shfl_xor(udw, 4);  uu += __shfl_xor(uu, 4);
                    udw += __shfl_xor(udw, 8);  uu += __shfl_xor(uu, 8);
                    if (m16 == 0) {
                        part[(w * 16 + row) * 2 + 0] = udw;
                        part[(w * 16 + row) * 2 + 1] = uu;
                    }
                }
                if (w == 0 && l < 16) {   // t slot for next step's drift
                    unsigned short th = rne_bf16(tn);
                    unsigned short tl = rne_bf16(tn - bf16_f(th));
                    xa[(4 * 2 + 0) * 512 + l * 8 + 0] = (short)th;
                    xa[(4 * 2 + 1) * 512 + l * 8 + 0] = (short)tl;
                }
            }
            __syncthreads();   // barrier #3
        }
    }

    // ---- final a1/a2 for step NSTEPS-1 ----
    if (tid < 16) {
        float sudw = 0.f, suu = 0.f;
        #pragma unroll
        for (int wv = 0; wv < 8; ++wv) {
            sudw += part[(wv * 16 + tid) * 2 + 0];
            suu  += part[(wv * 16 + tid) * 2 + 1];
        }
        float tcf = (float)NSTEPS * 0.01f;
        float tpf = (float)(NSTEPS - 1) * 0.01f;
        float dtp = tcf - tpf;
        a1 += sudw;
        a2 = fmaf(suu * 0.5f, dtp, a2);
        float* tro = out + ((size_t)NSTEPS * BATCHN + row0 + tid) * 130;
        tro[128] = a1;
        tro[129] = a2;
    }
}

extern "C" void kernel_launch(void* const* d_in, const int* in_sizes, int n_in,
                              void* d_out, int out_size, void* d_ws, size_t ws_size,
                              hipStream_t stream) {
    const float* noise = (const float*)d_in[0];
    const float* W1    = (const float*)d_in[1];
    const float* b1    = (const float*)d_in[2];
    const float* W2    = (const float*)d_in[3];
    const float* b2    = (const float*)d_in[4];
    const float* W3    = (const float*)d_in[5];
    const float* b3    = (const float*)d_in[6];
    float* out = (float*)d_out;
    short* ws  = (short*)d_ws;   // needs 272*2048 = 557056 bytes

    hipLaunchKernelGGL(prep_weights, dim3(68), dim3(256), 0, stream, W1, W2, W3, ws);
    hipLaunchKernelGGL(sde_mfma_kernel, dim3(BATCHN / 16), dim3(1024), 0, stream,
                       noise, b1, b2, b3, ws, out);
}

// Round 2
// 3154.235 us; speedup vs baseline: 1.0031x; 1.0031x over previous
//
#include <hip/hip_runtime.h>
#include <math.h>

#define NSTEPS 100
#define BATCHN 4096

typedef __attribute__((ext_vector_type(8))) short bf16x8;   // 8 x bf16 (4 VGPRs)
typedef __attribute__((ext_vector_type(4))) float f32x4;

#define MFMA16(a, b, c) __builtin_amdgcn_mfma_f32_16x16x32_bf16(a, b, c, 0, 0, 0)

__device__ __forceinline__ unsigned short rne_bf16(float x) {
    unsigned u = __float_as_uint(x);
    return (unsigned short)((u + 0x7FFFu + ((u >> 16) & 1u)) >> 16);
}
__device__ __forceinline__ float bf16_f(unsigned short h) {
    return __uint_as_float(((unsigned)h) << 16);
}
__device__ __forceinline__ float gelu_f(float x) {
    float x3 = x * x * x;
    float e = __expf(-1.5957691216057308f * (x + 0.044715f * x3));
    return x / (1.0f + e);
}

// ---------------------------------------------------------------------------
// Prep: swizzle W1/W2/W3 (fp32) into bf16 hi/lo B-fragment layout in ws.
// (unchanged from verified kernel)
// ---------------------------------------------------------------------------
__global__ __launch_bounds__(256) void prep_weights(
    const float* __restrict__ W1, const float* __restrict__ W2,
    const float* __restrict__ W3, short* __restrict__ ws)
{
    int g = blockIdx.x * 256 + threadIdx.x;
    if (g >= 272 * 64) return;
    int fp = g >> 6, l = g & 63;
    int m = l & 15, kq = (l >> 4) * 8;
    const float* W; int ndim, kdim, nt, kt;
    if (fp < 80)       { W = W1; ndim = 256; kdim = 129; nt = fp / 5;          kt = fp % 5; }
    else if (fp < 208) { W = W2; ndim = 256; kdim = 256; nt = (fp - 80) >> 3;  kt = (fp - 80) & 7; }
    else               { W = W3; ndim = 128; kdim = 256; nt = (fp - 208) >> 3; kt = (fp - 208) & 7; }
    int n = nt * 16 + m;
    bf16x8 vh, vl;
    #pragma unroll
    for (int j = 0; j < 8; ++j) {
        int k = kt * 32 + kq + j;
        float v = (k < kdim) ? W[k * ndim + n] : 0.f;
        unsigned short h = rne_bf16(v);
        float r = v - bf16_f(h);
        vh[j] = (short)h;
        vl[j] = (short)rne_bf16(r);
    }
    short* base = ws + (size_t)fp * 1024 + l * 8;
    *(bf16x8*)base = vh;
    *(bf16x8*)(base + 512) = vl;
}

// ---------------------------------------------------------------------------
// Main persistent kernel: 256 blocks x 1024 threads (16 waves), 16 rows/block,
// 100 steps. Round-2 change: pin waves/EU to 4 so the compiler allocates up
// to 128 VGPRs/wave (grid = 1 block/CU, so the old 64-VGPR cap bought zero
// occupancy and spilled all weight-prefetch arrays to scratch: +2.7 GB
// WRITE_SIZE, +1.7 GB FETCH_SIZE in round 1).
// ---------------------------------------------------------------------------
__global__
__attribute__((amdgpu_flat_work_group_size(1024, 1024), amdgpu_waves_per_eu(4, 4)))
void sde_mfma_kernel(
    const float* __restrict__ noise,
    const float* __restrict__ b1, const float* __restrict__ b2,
    const float* __restrict__ b3, const short* __restrict__ ws,
    float* __restrict__ out)
{
    __shared__ short xa [5 * 2 * 512];   // x,t A-frags (K=160), hi/lo
    __shared__ short h1a[8 * 2 * 512];   // h1 (K=256)
    __shared__ short h2a[8 * 2 * 512];   // h2 (K=256)
    __shared__ float part[8 * 16 * 2];   // per-wave row partials (udw, uu)

    const int tid  = threadIdx.x;
    const int w    = tid >> 6;          // wave 0..15
    const int l    = tid & 63;          // lane
    const int m16  = l & 15;
    const int q    = l >> 4;            // quad
    const int row0 = blockIdx.x * 16;

    // init
    for (int i = tid; i < 5 * 2 * 512; i += 1024) xa[i] = 0;
    {   // traj[0] rows for this block (x=0, a1=a2=0)
        float* t0 = out + (size_t)row0 * 130;
        for (int i = tid; i < 16 * 130; i += 1024) t0[i] = 0.f;
    }
    if (blockIdx.x == 0 && tid <= NSTEPS)
        out[(size_t)(NSTEPS + 1) * BATCHN * 130 + tid] = (float)tid * 0.01f;

    float a1 = 0.f, a2 = 0.f;                 // live in tid<16 threads
    const float bias1 = b1[w * 16 + m16];
    const float bias2 = b2[w * 16 + m16];
    const float bias3 = b3[(w & 7) * 16 + m16];

    // persistent W1 fragments (40 VGPRs)
    bf16x8 w1h[5], w1l[5];
    #pragma unroll
    for (int kt = 0; kt < 5; ++kt) {
        const short* bp = ws + (size_t)(w * 5 + kt) * 1024 + l * 8;
        w1h[kt] = *(const bf16x8*)bp;
        w1l[kt] = *(const bf16x8*)(bp + 512);
    }

    float xreg[4] = {0.f, 0.f, 0.f, 0.f};     // fp32 master state (w<8)
    float nzv[4];                              // prefetched noise (w<8)

    __syncthreads();

    for (int step = 0; step < NSTEPS; ++step) {
        const float tn   = (float)(step + 1) * 0.01f;
        const float tc   = (float)step * 0.01f;
        const float dt   = tn - tc;
        const float sqdt = sqrtf(dt);

        // ---- finish PREVIOUS step's a1/a2 (overlaps phase 1; race-safe:
        //      part's next writers must pass barriers #1,#2 first) ----
        if (step > 0 && tid < 16) {
            float sudw = 0.f, suu = 0.f;
            #pragma unroll
            for (int wv = 0; wv < 8; ++wv) {
                sudw += part[(wv * 16 + tid) * 2 + 0];
                suu  += part[(wv * 16 + tid) * 2 + 1];
            }
            float tp  = (float)(step - 1) * 0.01f;
            float dtp = tc - tp;
            a1 += sudw;                        // gamma = 1
            a2 = fmaf(suu * 0.5f, dtp, a2);
            float* tro = out + ((size_t)step * BATCHN + row0 + tid) * 130;
            tro[128] = a1;
            tro[129] = a2;
        }

        // ---- noise prefetch for THIS step (consumed in update) ----
        if (w < 8) {
            const float* nz = noise + ((size_t)step * BATCHN + row0) * 128 + (w * 16 + m16);
            #pragma unroll
            for (int r = 0; r < 4; ++r)
                nzv[r] = __builtin_nontemporal_load(&nz[(q * 4 + r) * 128]);
        }

        // ---- phase 1: h1 = gelu([x,t] @ W1 + b1), nt = w, K-tiles 5 ----
        {
            f32x4 accA = {0.f, 0.f, 0.f, 0.f};
            f32x4 accB = {0.f, 0.f, 0.f, 0.f};
            #pragma unroll
            for (int kt = 0; kt < 5; ++kt) {
                bf16x8 ah = *(const bf16x8*)&xa[(kt * 2 + 0) * 512 + l * 8];
                bf16x8 al = *(const bf16x8*)&xa[(kt * 2 + 1) * 512 + l * 8];
                if (kt & 1) {
                    accB = MFMA16(ah, w1h[kt], accB);
                    accB = MFMA16(al, w1h[kt], accB);
                    accB = MFMA16(ah, w1l[kt], accB);
                } else {
                    accA = MFMA16(ah, w1h[kt], accA);
                    accA = MFMA16(al, w1h[kt], accA);
                    accA = MFMA16(ah, w1l[kt], accA);
                }
            }
            f32x4 acc = accA + accB;

            // prefetch W2 (64 VGPRs in flight; W1 now dead)
            bf16x8 w2h[8], w2l[8];
            #pragma unroll
            for (int kt = 0; kt < 8; ++kt) {
                const short* bp = ws + (size_t)(80 + w * 8 + kt) * 1024 + l * 8;
                w2h[kt] = *(const bf16x8*)bp;
                w2l[kt] = *(const bf16x8*)(bp + 512);
            }

            // epilogue 1
            {
                const int ktw   = w >> 1;
                const int gbase = ((w & 1) * 2 + (m16 >> 3)) * 16;
                const int jj    = m16 & 7;
                #pragma unroll
                for (int r = 0; r < 4; ++r) {
                    float h = gelu_f(acc[r] + bias1);
                    unsigned short hh = rne_bf16(h);
                    unsigned short hl = rne_bf16(h - bf16_f(hh));
                    int lp = gbase + q * 4 + r;
                    h1a[(ktw * 2 + 0) * 512 + lp * 8 + jj] = (short)hh;
                    h1a[(ktw * 2 + 1) * 512 + lp * 8 + jj] = (short)hl;
                }
            }
            __syncthreads();   // barrier #1

            // ---- phase 2: h2 = gelu(h1 @ W2 + b2), nt = w, K-tiles 8 ----
            f32x4 acc2A = {0.f, 0.f, 0.f, 0.f};
            f32x4 acc2B = {0.f, 0.f, 0.f, 0.f};
            #pragma unroll
            for (int kt = 0; kt < 8; ++kt) {
                bf16x8 ah = *(const bf16x8*)&h1a[(kt * 2 + 0) * 512 + l * 8];
                bf16x8 al = *(const bf16x8*)&h1a[(kt * 2 + 1) * 512 + l * 8];
                if (kt & 1) {
                    acc2B = MFMA16(ah, w2h[kt], acc2B);
                    acc2B = MFMA16(al, w2h[kt], acc2B);
                    acc2B = MFMA16(ah, w2l[kt], acc2B);
                } else {
                    acc2A = MFMA16(ah, w2h[kt], acc2A);
                    acc2A = MFMA16(al, w2h[kt], acc2A);
                    acc2A = MFMA16(ah, w2l[kt], acc2A);
                }
            }
            f32x4 acc2 = acc2A + acc2B;

            // prefetch W3 (w<8) or reload next-step W1 (w>=8)
            bf16x8 w3h[8], w3l[8];
            if (w < 8) {
                #pragma unroll
                for (int kt = 0; kt < 8; ++kt) {
                    const short* bp = ws + (size_t)(208 + w * 8 + kt) * 1024 + l * 8;
                    w3h[kt] = *(const bf16x8*)bp;
                    w3l[kt] = *(const bf16x8*)(bp + 512);
                }
            } else {
                #pragma unroll
                for (int kt = 0; kt < 5; ++kt) {
                    const short* bp = ws + (size_t)(w * 5 + kt) * 1024 + l * 8;
                    w1h[kt] = *(const bf16x8*)bp;
                    w1l[kt] = *(const bf16x8*)(bp + 512);
                }
            }

            // epilogue 2
            {
                const int ktw   = w >> 1;
                const int gbase = ((w & 1) * 2 + (m16 >> 3)) * 16;
                const int jj    = m16 & 7;
                #pragma unroll
                for (int r = 0; r < 4; ++r) {
                    float h = gelu_f(acc2[r] + bias2);
                    unsigned short hh = rne_bf16(h);
                    unsigned short hl = rne_bf16(h - bf16_f(hh));
                    int lp = gbase + q * 4 + r;
                    h2a[(ktw * 2 + 0) * 512 + lp * 8 + jj] = (short)hh;
                    h2a[(ktw * 2 + 1) * 512 + lp * 8 + jj] = (short)hl;
                }
            }
            __syncthreads();   // barrier #2

            // ---- phase 3 (full K) + update, waves 0-7 only ----
            if (w < 8) {
                f32x4 a3A = {0.f, 0.f, 0.f, 0.f};
                f32x4 a3B = {0.f, 0.f, 0.f, 0.f};
                #pragma unroll
                for (int kt = 0; kt < 8; ++kt) {
                    bf16x8 ah = *(const bf16x8*)&h2a[(kt * 2 + 0) * 512 + l * 8];
                    bf16x8 al = *(const bf16x8*)&h2a[(kt * 2 + 1) * 512 + l * 8];
                    if (kt & 1) {
                        a3B = MFMA16(ah, w3h[kt], a3B);
                        a3B = MFMA16(al, w3h[kt], a3B);
                        a3B = MFMA16(ah, w3l[kt], a3B);
                    } else {
                        a3A = MFMA16(ah, w3h[kt], a3A);
                        a3A = MFMA16(al, w3h[kt], a3A);
                        a3A = MFMA16(ah, w3l[kt], a3A);
                    }
                }
                f32x4 acc3 = a3A + a3B;

                // reload next-step W1 (W3 now dead)
                #pragma unroll
                for (int kt = 0; kt < 5; ++kt) {
                    const short* bp = ws + (size_t)(w * 5 + kt) * 1024 + l * 8;
                    w1h[kt] = *(const bf16x8*)bp;
                    w1l[kt] = *(const bf16x8*)(bp + 512);
                }

                // update: x += u*dt + dW; partial sums; refresh xa
                const int c = w * 16 + m16;
                float* tro = out + ((size_t)(step + 1) * BATCHN + row0) * 130;
                const int ktx = c >> 5;
                const int lpb = ((c & 31) >> 3) * 16;
                const int jx  = c & 7;
                #pragma unroll
                for (int r = 0; r < 4; ++r) {
                    int row = q * 4 + r;
                    float u  = acc3[r] + bias3;
                    float dW = sqdt * nzv[r];
                    float xn = fmaf(u, dt, xreg[r]) + dW;
                    xreg[r] = xn;
                    __builtin_nontemporal_store(xn, &tro[row * 130 + c]);
                    unsigned short xh = rne_bf16(xn);
                    unsigned short xl = rne_bf16(xn - bf16_f(xh));
                    int lp = lpb + row;
                    xa[(ktx * 2 + 0) * 512 + lp * 8 + jx] = (short)xh;
                    xa[(ktx * 2 + 1) * 512 + lp * 8 + jx] = (short)xl;
                    float udw = u * dW, uu = u * u;
                    udw += __shfl_xor(udw, 1);  uu += __shfl_xor(uu, 1);
                    udw += __shfl_xor(udw, 2);  uu += __shfl_xor(uu, 2);
                    udw += __shfl_xor(udw, 4);  uu += __shfl_xor(uu, 4);
                    udw += __shfl_xor(udw, 8);  uu += __shfl_xor(uu, 8);
                    if (m16 == 0) {
                        part[(w * 16 + row) * 2 + 0] = udw;
                        part[(w * 16 + row) * 2 + 1] = uu;
                    }
                }
                if (w == 0 && l < 16) {   // t slot for next step's drift
                    unsigned short th = rne_bf16(tn);
                    unsigned short tl = rne_bf16(tn - bf16_f(th));
                    xa[(4 * 2 + 0) * 512 + l * 8 + 0] = (short)th;
                    xa[(4 * 2 + 1) * 512 + l * 8 + 0] = (short)tl;
                }
            }
            __syncthreads();   // barrier #3
        }
    }

    // ---- final a1/a2 for step NSTEPS-1 ----
    if (tid < 16) {
        float sudw = 0.f, suu = 0.f;
        #pragma unroll
        for (int wv = 0; wv < 8; ++wv) {
            sudw += part[(wv * 16 + tid) * 2 + 0];
            suu  += part[(wv * 16 + tid) * 2 + 1];
        }
        float tcf = (float)NSTEPS * 0.01f;
        float tpf = (float)(NSTEPS - 1) * 0.01f;
        float dtp = tcf - tpf;
        a1 += sudw;
        a2 = fmaf(suu * 0.5f, dtp, a2);
        float* tro = out + ((size_t)NSTEPS * BATCHN + row0 + tid) * 130;
        tro[128] = a1;
        tro[129] = a2;
    }
}

extern "C" void kernel_launch(void* const* d_in, const int* in_sizes, int n_in,
                              void* d_out, int out_size, void* d_ws, size_t ws_size,
                              hipStream_t stream) {
    const float* noise = (const float*)d_in[0];
    const float* W1    = (const float*)d_in[1];
    const float* b1    = (const float*)d_in[2];
    const float* W2    = (const float*)d_in[3];
    const float* b2    = (const float*)d_in[4];
    const float* W3    = (const float*)d_in[5];
    const float* b3    = (const float*)d_in[6];
    float* out = (float*)d_out;
    short* ws  = (short*)d_ws;   // needs 272*2048 = 557056 bytes

    hipLaunchKernelGGL(prep_weights, dim3(68), dim3(256), 0, stream, W1, W2, W3, ws);
    hipLaunchKernelGGL(sde_mfma_kernel, dim3(BATCHN / 16), dim3(1024), 0, stream,
                       noise, b1, b2, b3, ws, out);
}

// Round 3
// 1626.902 us; speedup vs baseline: 1.9448x; 1.9388x over previous
//
#include <hip/hip_runtime.h>
#include <math.h>

#define NSTEPS 100
#define BATCHN 4096

typedef __attribute__((ext_vector_type(8))) short bf16x8;   // 8 x bf16 (4 VGPRs)
typedef __attribute__((ext_vector_type(4))) float f32x4;

#define MFMA16(a, b, c) __builtin_amdgcn_mfma_f32_16x16x32_bf16(a, b, c, 0, 0, 0)

__device__ __forceinline__ unsigned short rne_bf16(float x) {
    unsigned u = __float_as_uint(x);
    return (unsigned short)((u + 0x7FFFu + ((u >> 16) & 1u)) >> 16);
}
__device__ __forceinline__ float bf16_f(unsigned short h) {
    return __uint_as_float(((unsigned)h) << 16);
}
__device__ __forceinline__ float gelu_f(float x) {
    float x3 = x * x * x;
    float e = __expf(-1.5957691216057308f * (x + 0.044715f * x3));
    return x / (1.0f + e);
}

// ---------------------------------------------------------------------------
// Prep: swizzle W1/W2/W3 (fp32) into bf16 hi/lo B-fragment layout in ws.
// Layout unchanged from the verified kernel; W1's kt=4 tile (t-row) is still
// written but never read by the main kernel (t handled via fp32 bias).
// ---------------------------------------------------------------------------
__global__ __launch_bounds__(256) void prep_weights(
    const float* __restrict__ W1, const float* __restrict__ W2,
    const float* __restrict__ W3, short* __restrict__ ws)
{
    int g = blockIdx.x * 256 + threadIdx.x;
    if (g >= 272 * 64) return;
    int fp = g >> 6, l = g & 63;
    int m = l & 15, kq = (l >> 4) * 8;
    const float* W; int ndim, kdim, nt, kt;
    if (fp < 80)       { W = W1; ndim = 256; kdim = 129; nt = fp / 5;          kt = fp % 5; }
    else if (fp < 208) { W = W2; ndim = 256; kdim = 256; nt = (fp - 80) >> 3;  kt = (fp - 80) & 7; }
    else               { W = W3; ndim = 128; kdim = 256; nt = (fp - 208) >> 3; kt = (fp - 208) & 7; }
    int n = nt * 16 + m;
    bf16x8 vh, vl;
    #pragma unroll
    for (int j = 0; j < 8; ++j) {
        int k = kt * 32 + kq + j;
        float v = (k < kdim) ? W[k * ndim + n] : 0.f;
        unsigned short h = rne_bf16(v);
        float r = v - bf16_f(h);
        vh[j] = (short)h;
        vl[j] = (short)rne_bf16(r);
    }
    short* base = ws + (size_t)fp * 1024 + l * 8;
    *(bf16x8*)base = vh;
    *(bf16x8*)(base + 512) = vl;
}

// ---------------------------------------------------------------------------
// Main persistent kernel: 256 blocks x 1024 threads (16 waves), 16 rows/block,
// 100 steps. Round-3: verified round-0 structure (streamed weights, 64 VGPR,
// no scratch) + register-cheap latency fixes:
//  - NT hints on out stores / noise loads (stop L2 pollution of ws)
//  - noise prefetched at top of step (HBM latency hidden under phases 1-3)
//  - t-row of W1 folded into bias in fp32 (phase 1: 5 -> 4 K-tiles)
//  - a1/a2 reduce deferred to next step top (barriers 5 -> 4)
//  - fp32 master state in registers instead of LDS
// ---------------------------------------------------------------------------
__global__ __launch_bounds__(1024) void sde_mfma_kernel(
    const float* __restrict__ noise, const float* __restrict__ W1f,
    const float* __restrict__ b1, const float* __restrict__ b2,
    const float* __restrict__ b3, const short* __restrict__ ws,
    float* __restrict__ out)
{
    __shared__ short xa [4 * 2 * 512];   // x A-frags (K=128), hi/lo
    __shared__ short h1a[8 * 2 * 512];   // h1 (K=256)
    __shared__ short h2a[8 * 2 * 512];   // h2 (K=256)
    __shared__ float p3  [8 * 64 * 4];   // phase-3 split-K partials
    __shared__ float part[8 * 16 * 2];   // per-wave row partials (udw, uu)

    const int tid  = threadIdx.x;
    const int w    = tid >> 6;          // wave 0..15
    const int l    = tid & 63;          // lane
    const int m16  = l & 15;
    const int q    = l >> 4;            // quad
    const int row0 = blockIdx.x * 16;

    // init
    for (int i = tid; i < 4 * 2 * 512; i += 1024) xa[i] = 0;
    {   // traj[0] rows for this block (x=0, a1=a2=0)
        float* t0 = out + (size_t)row0 * 130;
        for (int i = tid; i < 16 * 130; i += 1024)
            __builtin_nontemporal_store(0.f, &t0[i]);
    }
    if (blockIdx.x == 0 && tid <= NSTEPS)
        out[(size_t)(NSTEPS + 1) * BATCHN * 130 + tid] = (float)tid * 0.01f;

    float a1 = 0.f, a2 = 0.f;                 // live in tid<16 threads
    const float bias1 = b1[w * 16 + m16];
    const float bias2 = b2[w * 16 + m16];
    const int nt3   = w & 7;
    const int khalf = w >> 3;
    const float bias3 = b3[nt3 * 16 + m16];
    const float w1t   = W1f[128 * 256 + w * 16 + m16];   // W1[128][n]

    float xreg[4] = {0.f, 0.f, 0.f, 0.f};     // fp32 master state (w<8)
    float nzv[4];                              // prefetched noise (w<8)

    __syncthreads();

    for (int step = 0; step < NSTEPS; ++step) {
        const float tn   = (float)(step + 1) * 0.01f;
        const float tc   = (float)step * 0.01f;
        const float dt   = tn - tc;
        const float sqdt = sqrtf(dt);

        // ---- finish PREVIOUS step's a1/a2 (overlaps phase 1; race-safe:
        //      part's next writers must pass barriers #1,#2,#3 first) ----
        if (step > 0 && tid < 16) {
            float sudw = 0.f, suu = 0.f;
            #pragma unroll
            for (int wv = 0; wv < 8; ++wv) {
                sudw += part[(wv * 16 + tid) * 2 + 0];
                suu  += part[(wv * 16 + tid) * 2 + 1];
            }
            float tp  = (float)(step - 1) * 0.01f;
            float dtp = tc - tp;
            a1 += sudw;                        // gamma = 1
            a2 = fmaf(suu * 0.5f, dtp, a2);
            float* tro = out + ((size_t)step * BATCHN + row0 + tid) * 130;
            __builtin_nontemporal_store(a1, &tro[128]);
            __builtin_nontemporal_store(a2, &tro[129]);
        }

        // ---- noise prefetch for THIS step (consumed in update) ----
        if (!khalf) {
            const float* nz = noise + ((size_t)step * BATCHN + row0) * 128 + (nt3 * 16 + m16);
            #pragma unroll
            for (int r = 0; r < 4; ++r)
                nzv[r] = __builtin_nontemporal_load(&nz[(q * 4 + r) * 128]);
        }

        // t-row of W1 folded into bias (exact fp32)
        const float hb1 = fmaf(tc, w1t, bias1);

        // ---- phase 1: h1 = gelu([x,t] @ W1 + b1), nt = w, K-tiles 4 ----
        {
            f32x4 acc = {0.f, 0.f, 0.f, 0.f};
            #pragma unroll
            for (int kt = 0; kt < 4; ++kt) {
                bf16x8 ah = *(const bf16x8*)&xa[(kt * 2 + 0) * 512 + l * 8];
                bf16x8 al = *(const bf16x8*)&xa[(kt * 2 + 1) * 512 + l * 8];
                const short* bp = ws + (size_t)(w * 5 + kt) * 1024 + l * 8;
                bf16x8 bh = *(const bf16x8*)bp;
                bf16x8 bl = *(const bf16x8*)(bp + 512);
                acc = MFMA16(ah, bh, acc);
                acc = MFMA16(al, bh, acc);
                acc = MFMA16(ah, bl, acc);
            }
            const int ktw   = w >> 1;
            const int gbase = ((w & 1) * 2 + (m16 >> 3)) * 16;
            const int jj    = m16 & 7;
            #pragma unroll
            for (int r = 0; r < 4; ++r) {
                float h = gelu_f(acc[r] + hb1);
                unsigned short hh = rne_bf16(h);
                unsigned short hl = rne_bf16(h - bf16_f(hh));
                int lp = gbase + q * 4 + r;
                h1a[(ktw * 2 + 0) * 512 + lp * 8 + jj] = (short)hh;
                h1a[(ktw * 2 + 1) * 512 + lp * 8 + jj] = (short)hl;
            }
        }
        __syncthreads();   // barrier #1

        // ---- phase 2: h2 = gelu(h1 @ W2 + b2), nt = w, K-tiles 8 ----
        {
            f32x4 acc = {0.f, 0.f, 0.f, 0.f};
            #pragma unroll
            for (int kt = 0; kt < 8; ++kt) {
                bf16x8 ah = *(const bf16x8*)&h1a[(kt * 2 + 0) * 512 + l * 8];
                bf16x8 al = *(const bf16x8*)&h1a[(kt * 2 + 1) * 512 + l * 8];
                const short* bp = ws + (size_t)(80 + w * 8 + kt) * 1024 + l * 8;
                bf16x8 bh = *(const bf16x8*)bp;
                bf16x8 bl = *(const bf16x8*)(bp + 512);
                acc = MFMA16(ah, bh, acc);
                acc = MFMA16(al, bh, acc);
                acc = MFMA16(ah, bl, acc);
            }
            const int ktw   = w >> 1;
            const int gbase = ((w & 1) * 2 + (m16 >> 3)) * 16;
            const int jj    = m16 & 7;
            #pragma unroll
            for (int r = 0; r < 4; ++r) {
                float h = gelu_f(acc[r] + bias2);
                unsigned short hh = rne_bf16(h);
                unsigned short hl = rne_bf16(h - bf16_f(hh));
                int lp = gbase + q * 4 + r;
                h2a[(ktw * 2 + 0) * 512 + lp * 8 + jj] = (short)hh;
                h2a[(ktw * 2 + 1) * 512 + lp * 8 + jj] = (short)hl;
            }
        }
        __syncthreads();   // barrier #2

        // ---- phase 3: u = h2 @ W3 + b3; split-K across wave halves ----
        f32x4 acc3 = {0.f, 0.f, 0.f, 0.f};
        {
            const int kt0 = khalf * 4;
            #pragma unroll
            for (int kk = 0; kk < 4; ++kk) {
                int kt = kt0 + kk;
                bf16x8 ah = *(const bf16x8*)&h2a[(kt * 2 + 0) * 512 + l * 8];
                bf16x8 al = *(const bf16x8*)&h2a[(kt * 2 + 1) * 512 + l * 8];
                const short* bp = ws + (size_t)(208 + nt3 * 8 + kt) * 1024 + l * 8;
                bf16x8 bh = *(const bf16x8*)bp;
                bf16x8 bl = *(const bf16x8*)(bp + 512);
                acc3 = MFMA16(ah, bh, acc3);
                acc3 = MFMA16(al, bh, acc3);
                acc3 = MFMA16(ah, bl, acc3);
            }
            if (khalf) *(f32x4*)&p3[(nt3 * 64 + l) * 4] = acc3;
        }
        __syncthreads();   // barrier #3

        // ---- update (waves 0-7): x += u*dt + dW; partial sums; refresh xa ----
        if (!khalf) {
            f32x4 o = *(const f32x4*)&p3[(nt3 * 64 + l) * 4];
            const int c = nt3 * 16 + m16;
            float* tro = out + ((size_t)(step + 1) * BATCHN + row0) * 130;
            const int ktx = c >> 5;
            const int lpb = ((c & 31) >> 3) * 16;
            const int jx  = c & 7;
            #pragma unroll
            for (int r = 0; r < 4; ++r) {
                int row = q * 4 + r;
                float u  = acc3[r] + o[r] + bias3;
                float dW = sqdt * nzv[r];
                float xn = fmaf(u, dt, xreg[r]) + dW;
                xreg[r] = xn;
                __builtin_nontemporal_store(xn, &tro[row * 130 + c]);
                unsigned short xh = rne_bf16(xn);
                unsigned short xl = rne_bf16(xn - bf16_f(xh));
                int lp = lpb + row;
                xa[(ktx * 2 + 0) * 512 + lp * 8 + jx] = (short)xh;
                xa[(ktx * 2 + 1) * 512 + lp * 8 + jx] = (short)xl;
                float udw = u * dW, uu = u * u;
                udw += __shfl_xor(udw, 1);  uu += __shfl_xor(uu, 1);
                udw += __shfl_xor(udw, 2);  uu += __shfl_xor(uu, 2);
                udw += __shfl_xor(udw, 4);  uu += __shfl_xor(uu, 4);
                udw += __shfl_xor(udw, 8);  uu += __shfl_xor(uu, 8);
                if (m16 == 0) {
                    part[(w * 16 + row) * 2 + 0] = udw;
                    part[(w * 16 + row) * 2 + 1] = uu;
                }
            }
        }
        __syncthreads();   // barrier #4
    }

    // ---- final a1/a2 for step NSTEPS-1 ----
    if (tid < 16) {
        float sudw = 0.f, suu = 0.f;
        #pragma unroll
        for (int wv = 0; wv < 8; ++wv) {
            sudw += part[(wv * 16 + tid) * 2 + 0];
            suu  += part[(wv * 16 + tid) * 2 + 1];
        }
        float tcf = (float)NSTEPS * 0.01f;
        float tpf = (float)(NSTEPS - 1) * 0.01f;
        float dtp = tcf - tpf;
        a1 += sudw;
        a2 = fmaf(suu * 0.5f, dtp, a2);
        float* tro = out + ((size_t)NSTEPS * BATCHN + row0 + tid) * 130;
        __builtin_nontemporal_store(a1, &tro[128]);
        __builtin_nontemporal_store(a2, &tro[129]);
    }
}

extern "C" void kernel_launch(void* const* d_in, const int* in_sizes, int n_in,
                              void* d_out, int out_size, void* d_ws, size_t ws_size,
                              hipStream_t stream) {
    const float* noise = (const float*)d_in[0];
    const float* W1    = (const float*)d_in[1];
    const float* b1    = (const float*)d_in[2];
    const float* W2    = (const float*)d_in[3];
    const float* b2    = (const float*)d_in[4];
    const float* W3    = (const float*)d_in[5];
    const float* b3    = (const float*)d_in[6];
    float* out = (float*)d_out;
    short* ws  = (short*)d_ws;   // needs 272*2048 = 557056 bytes

    hipLaunchKernelGGL(prep_weights, dim3(68), dim3(256), 0, stream, W1, W2, W3, ws);
    hipLaunchKernelGGL(sde_mfma_kernel, dim3(BATCHN / 16), dim3(1024), 0, stream,
                       noise, W1, b1, b2, b3, ws, out);
}

// Round 4
// 1140.319 us; speedup vs baseline: 2.7746x; 1.4267x over previous
//
#include <hip/hip_runtime.h>
#include <math.h>

#define NSTEPS 100
#define BATCHN 4096

typedef __attribute__((ext_vector_type(8))) short bf16x8;   // 8 x bf16 (4 VGPRs)
typedef __attribute__((ext_vector_type(4))) float f32x4;

#define MFMA16(a, b, c) __builtin_amdgcn_mfma_f32_16x16x32_bf16(a, b, c, 0, 0, 0)

// counted vmem waits for the DMA ring (see per-phase count audits in comments)
#define WAITVM4 asm volatile("s_waitcnt vmcnt(4)" ::: "memory")
#define WAITVM2 asm volatile("s_waitcnt vmcnt(2)" ::: "memory")
#define WAITVM0 asm volatile("s_waitcnt vmcnt(0)" ::: "memory")
#define SCHEDB  __builtin_amdgcn_sched_barrier(0)

__device__ __forceinline__ unsigned short rne_bf16(float x) {
    unsigned u = __float_as_uint(x);
    return (unsigned short)((u + 0x7FFFu + ((u >> 16) & 1u)) >> 16);
}
__device__ __forceinline__ float bf16_f(unsigned short h) {
    return __uint_as_float(((unsigned)h) << 16);
}
__device__ __forceinline__ float gelu_f(float x) {
    float x3 = x * x * x;
    float e = __expf(-1.5957691216057308f * (x + 0.044715f * x3));
    return x / (1.0f + e);
}

// ---------------------------------------------------------------------------
// Prep: swizzle W1/W2/W3 (fp32) into bf16 hi/lo B-fragment layout in ws.
// (unchanged from verified kernel)
// ---------------------------------------------------------------------------
__global__ __launch_bounds__(256) void prep_weights(
    const float* __restrict__ W1, const float* __restrict__ W2,
    const float* __restrict__ W3, short* __restrict__ ws)
{
    int g = blockIdx.x * 256 + threadIdx.x;
    if (g >= 272 * 64) return;
    int fp = g >> 6, l = g & 63;
    int m = l & 15, kq = (l >> 4) * 8;
    const float* W; int ndim, kdim, nt, kt;
    if (fp < 80)       { W = W1; ndim = 256; kdim = 129; nt = fp / 5;          kt = fp % 5; }
    else if (fp < 208) { W = W2; ndim = 256; kdim = 256; nt = (fp - 80) >> 3;  kt = (fp - 80) & 7; }
    else               { W = W3; ndim = 128; kdim = 256; nt = (fp - 208) >> 3; kt = (fp - 208) & 7; }
    int n = nt * 16 + m;
    bf16x8 vh, vl;
    #pragma unroll
    for (int j = 0; j < 8; ++j) {
        int k = kt * 32 + kq + j;
        float v = (k < kdim) ? W[k * ndim + n] : 0.f;
        unsigned short h = rne_bf16(v);
        float r = v - bf16_f(h);
        vh[j] = (short)h;
        vl[j] = (short)rne_bf16(r);
    }
    short* base = ws + (size_t)fp * 1024 + l * 8;
    *(bf16x8*)base = vh;
    *(bf16x8*)(base + 512) = vl;
}

// ---------------------------------------------------------------------------
// Main persistent kernel: 256 blocks x 1024 threads (16 waves), 16 rows/block.
// Round-4: weights stream global->LDS via per-wave async DMA ring
// (global_load_lds, 3 slots x 2KB per wave), consumed with counted vmcnt.
// Ring is wave-private => no extra barriers; each phase's first 3 slices are
// pre-issued before the preceding __syncthreads (barrier drain completes them).
// ---------------------------------------------------------------------------
__global__ __launch_bounds__(1024) void sde_mfma_kernel(
    const float* __restrict__ noise, const float* __restrict__ W1f,
    const float* __restrict__ b1, const float* __restrict__ b2,
    const float* __restrict__ b3, const short* __restrict__ ws,
    float* __restrict__ out)
{
    __shared__ short ring[16 * 3 * 1024]; // 96 KB: per-wave 3-slot weight ring
    __shared__ short xa [4 * 2 * 512];    // x A-frags (K=128), hi/lo   (8 KB)
    __shared__ short h1a[8 * 2 * 512];    // h1 (K=256)                (16 KB)
    __shared__ short h2a[8 * 2 * 512];    // h2 (K=256)                (16 KB)
    __shared__ float p3  [8 * 64 * 4];    // phase-3 split-K partials   (8 KB)
    __shared__ float part[8 * 16 * 2];    // per-wave row partials      (1 KB)

    const int tid  = threadIdx.x;
    const int w    = tid >> 6;          // wave 0..15
    const int l    = tid & 63;          // lane
    const int m16  = l & 15;
    const int q    = l >> 4;            // quad
    const int row0 = blockIdx.x * 16;
    const int rb   = w * 3072;          // ring base (shorts) for this wave

    // stage one weight frag-pair (hi+lo, 2KB) into a ring slot (2 DMA ops)
    auto stage = [&](int fp, int slot) {
        const short* g = ws + (size_t)fp * 1024 + l * 8;
        short* d = (short*)&ring[rb + slot * 1024];
        __builtin_amdgcn_global_load_lds((const unsigned int*)g,         (unsigned int*)d,         16, 0, 0);
        __builtin_amdgcn_global_load_lds((const unsigned int*)(g + 512), (unsigned int*)(d + 512), 16, 0, 0);
    };
    // consume: A-frag (hi/lo) from abuf[kt], B-frag (hi/lo) from ring slot
    auto consume = [&](const short* abuf, int kt, int slot, f32x4& acc) {
        bf16x8 ah = *(const bf16x8*)&abuf[(kt * 2 + 0) * 512 + l * 8];
        bf16x8 al = *(const bf16x8*)&abuf[(kt * 2 + 1) * 512 + l * 8];
        const short* bp = &ring[rb + slot * 1024 + l * 8];
        bf16x8 bh = *(const bf16x8*)bp;
        bf16x8 bl = *(const bf16x8*)(bp + 512);
        acc = MFMA16(ah, bh, acc);
        acc = MFMA16(al, bh, acc);
        acc = MFMA16(ah, bl, acc);
    };

    // init
    for (int i = tid; i < 4 * 2 * 512; i += 1024) xa[i] = 0;
    {   // traj[0] rows for this block (x=0, a1=a2=0)
        float* t0 = out + (size_t)row0 * 130;
        for (int i = tid; i < 16 * 130; i += 1024)
            __builtin_nontemporal_store(0.f, &t0[i]);
    }
    if (blockIdx.x == 0 && tid <= NSTEPS)
        out[(size_t)(NSTEPS + 1) * BATCHN * 130 + tid] = (float)tid * 0.01f;

    float a1 = 0.f, a2 = 0.f;                 // live in tid<16 threads
    const float bias1 = b1[w * 16 + m16];
    const float bias2 = b2[w * 16 + m16];
    const int nt3   = w & 7;
    const int khalf = w >> 3;
    const float bias3 = b3[nt3 * 16 + m16];
    const float w1t   = W1f[128 * 256 + w * 16 + m16];   // W1[128][n]

    float xreg[4] = {0.f, 0.f, 0.f, 0.f};     // fp32 master state (w<8)
    float nzv[4];                              // prefetched noise

    // prologue: pre-stage phase-1 slices 0..2 (drained by the barrier below)
    stage(w * 5 + 0, 0);
    stage(w * 5 + 1, 1);
    stage(w * 5 + 2, 2);
    __syncthreads();

    for (int step = 0; step < NSTEPS; ++step) {
        const float tn   = (float)(step + 1) * 0.01f;
        const float tc   = (float)step * 0.01f;
        const float dt   = tn - tc;
        const float sqdt = sqrtf(dt);

        // ---- finish PREVIOUS step's a1/a2 (overlaps phase 1; race-safe) ----
        if (step > 0 && tid < 16) {
            float sudw = 0.f, suu = 0.f;
            #pragma unroll
            for (int wv = 0; wv < 8; ++wv) {
                sudw += part[(wv * 16 + tid) * 2 + 0];
                suu  += part[(wv * 16 + tid) * 2 + 1];
            }
            float tp  = (float)(step - 1) * 0.01f;
            float dtp = tc - tp;
            a1 += sudw;                        // gamma = 1
            a2 = fmaf(suu * 0.5f, dtp, a2);
            float* tro = out + ((size_t)step * BATCHN + row0 + tid) * 130;
            __builtin_nontemporal_store(a1, &tro[128]);
            __builtin_nontemporal_store(a2, &tro[129]);
        }

        const float hb1 = fmaf(tc, w1t, bias1);   // t-row of W1 folded into bias

        // ---- phase 1: h1 = gelu([x,t] @ W1 + b1), K-tiles 4 ----
        // slices 0..2 already resident (pre-staged before last barrier).
        {
            f32x4 acc = {0.f, 0.f, 0.f, 0.f};
            consume(xa, 0, 0, acc);
            SCHEDB; stage(w * 5 + 3, 0);          // s3 -> slot0
            // noise prefetch AFTER s3 so WAITVM4 below guarantees s3 done
            {
                const float* nz = noise + ((size_t)step * BATCHN + row0) * 128 + (nt3 * 16 + m16);
                #pragma unroll
                for (int r = 0; r < 4; ++r)
                    nzv[r] = __builtin_nontemporal_load(&nz[(q * 4 + r) * 128]);
            }
            consume(xa, 1, 1, acc);
            consume(xa, 2, 2, acc);
            // outstanding: {s3(2), noise(4)} = 6 -> vmcnt(4) => s3 complete
            WAITVM4; SCHEDB;
            consume(xa, 3, 0, acc);

            const int ktw   = w >> 1;
            const int gbase = ((w & 1) * 2 + (m16 >> 3)) * 16;
            const int jj    = m16 & 7;
            #pragma unroll
            for (int r = 0; r < 4; ++r) {
                float h = gelu_f(acc[r] + hb1);
                unsigned short hh = rne_bf16(h);
                unsigned short hl = rne_bf16(h - bf16_f(hh));
                int lp = gbase + q * 4 + r;
                h1a[(ktw * 2 + 0) * 512 + lp * 8 + jj] = (short)hh;
                h1a[(ktw * 2 + 1) * 512 + lp * 8 + jj] = (short)hl;
            }
            // pre-stage phase-2 slices 0..2 (drained by barrier #1)
            SCHEDB;
            stage(80 + w * 8 + 0, 0);
            stage(80 + w * 8 + 1, 1);
            stage(80 + w * 8 + 2, 2);
        }
        __syncthreads();   // barrier #1 (drains all outstanding vmem)

        // ---- phase 2: h2 = gelu(h1 @ W2 + b2), K-tiles 8 ----
        {
            const int f0 = 80 + w * 8;
            f32x4 acc = {0.f, 0.f, 0.f, 0.f};
            consume(h1a, 0, 0, acc); SCHEDB; stage(f0 + 3, 0);
            consume(h1a, 1, 1, acc); SCHEDB; stage(f0 + 4, 1);
            consume(h1a, 2, 2, acc); SCHEDB; stage(f0 + 5, 2);
            // {s3,s4,s5}=6 -> vmcnt(4) => s3 done
            WAITVM4; SCHEDB; consume(h1a, 3, 0, acc); SCHEDB; stage(f0 + 6, 0);
            // {s4,s5,s6}=6 -> vmcnt(4) => s4 done
            WAITVM4; SCHEDB; consume(h1a, 4, 1, acc); SCHEDB; stage(f0 + 7, 1);
            // {s5,s6,s7}=6 -> vmcnt(4) => s5 done
            WAITVM4; SCHEDB; consume(h1a, 5, 2, acc);
            // {s6,s7}=4 -> vmcnt(2) => s6 done
            WAITVM2; SCHEDB; consume(h1a, 6, 0, acc);
            // {s7}=2 -> vmcnt(0)
            WAITVM0; SCHEDB; consume(h1a, 7, 1, acc);

            const int ktw   = w >> 1;
            const int gbase = ((w & 1) * 2 + (m16 >> 3)) * 16;
            const int jj    = m16 & 7;
            #pragma unroll
            for (int r = 0; r < 4; ++r) {
                float h = gelu_f(acc[r] + bias2);
                unsigned short hh = rne_bf16(h);
                unsigned short hl = rne_bf16(h - bf16_f(hh));
                int lp = gbase + q * 4 + r;
                h2a[(ktw * 2 + 0) * 512 + lp * 8 + jj] = (short)hh;
                h2a[(ktw * 2 + 1) * 512 + lp * 8 + jj] = (short)hl;
            }
            // pre-stage phase-3 slices 0..2 (drained by barrier #2)
            SCHEDB;
            const int f3 = 208 + nt3 * 8 + khalf * 4;
            stage(f3 + 0, 0);
            stage(f3 + 1, 1);
            stage(f3 + 2, 2);
        }
        __syncthreads();   // barrier #2

        // ---- phase 3: u = h2 @ W3 + b3; split-K across wave halves ----
        f32x4 acc3 = {0.f, 0.f, 0.f, 0.f};
        {
            const int f3 = 208 + nt3 * 8 + khalf * 4;
            const int kb = khalf * 4;
            consume(h2a, kb + 0, 0, acc3);
            SCHEDB; stage(f3 + 3, 0);
            consume(h2a, kb + 1, 1, acc3);
            consume(h2a, kb + 2, 2, acc3);
            // only {s3}=2 outstanding; vmcnt(0) is the exact wait
            WAITVM0; SCHEDB;
            consume(h2a, kb + 3, 0, acc3);
            if (khalf) *(f32x4*)&p3[(nt3 * 64 + l) * 4] = acc3;
            // pre-stage NEXT step's phase-1 slices (drained by barrier #3)
            SCHEDB;
            stage(w * 5 + 0, 0);
            stage(w * 5 + 1, 1);
            stage(w * 5 + 2, 2);
        }
        __syncthreads();   // barrier #3

        // ---- update (waves 0-7): x += u*dt + dW; partial sums; refresh xa ----
        if (!khalf) {
            f32x4 o = *(const f32x4*)&p3[(nt3 * 64 + l) * 4];
            const int c = nt3 * 16 + m16;
            float* tro = out + ((size_t)(step + 1) * BATCHN + row0) * 130;
            const int ktx = c >> 5;
            const int lpb = ((c & 31) >> 3) * 16;
            const int jx  = c & 7;
            #pragma unroll
            for (int r = 0; r < 4; ++r) {
                int row = q * 4 + r;
                float u  = acc3[r] + o[r] + bias3;
                float dW = sqdt * nzv[r];
                float xn = fmaf(u, dt, xreg[r]) + dW;
                xreg[r] = xn;
                __builtin_nontemporal_store(xn, &tro[row * 130 + c]);
                unsigned short xh = rne_bf16(xn);
                unsigned short xl = rne_bf16(xn - bf16_f(xh));
                int lp = lpb + row;
                xa[(ktx * 2 + 0) * 512 + lp * 8 + jx] = (short)xh;
                xa[(ktx * 2 + 1) * 512 + lp * 8 + jx] = (short)xl;
                float udw = u * dW, uu = u * u;
                udw += __shfl_xor(udw, 1);  uu += __shfl_xor(uu, 1);
                udw += __shfl_xor(udw, 2);  uu += __shfl_xor(uu, 2);
                udw += __shfl_xor(udw, 4);  uu += __shfl_xor(uu, 4);
                udw += __shfl_xor(udw, 8);  uu += __shfl_xor(uu, 8);
                if (m16 == 0) {
                    part[(w * 16 + row) * 2 + 0] = udw;
                    part[(w * 16 + row) * 2 + 1] = uu;
                }
            }
        }
        __syncthreads();   // barrier #4
    }

    // ---- final a1/a2 for step NSTEPS-1 ----
    if (tid < 16) {
        float sudw = 0.f, suu = 0.f;
        #pragma unroll
        for (int wv = 0; wv < 8; ++wv) {
            sudw += part[(wv * 16 + tid) * 2 + 0];
            suu  += part[(wv * 16 + tid) * 2 + 1];
        }
        float tcf = (float)NSTEPS * 0.01f;
        float tpf = (float)(NSTEPS - 1) * 0.01f;
        float dtp = tcf - tpf;
        a1 += sudw;
        a2 = fmaf(suu * 0.5f, dtp, a2);
        float* tro = out + ((size_t)NSTEPS * BATCHN + row0 + tid) * 130;
        __builtin_nontemporal_store(a1, &tro[128]);
        __builtin_nontemporal_store(a2, &tro[129]);
    }
}

extern "C" void kernel_launch(void* const* d_in, const int* in_sizes, int n_in,
                              void* d_out, int out_size, void* d_ws, size_t ws_size,
                              hipStream_t stream) {
    const float* noise = (const float*)d_in[0];
    const float* W1    = (const float*)d_in[1];
    const float* b1    = (const float*)d_in[2];
    const float* W2    = (const float*)d_in[3];
    const float* b2    = (const float*)d_in[4];
    const float* W3    = (const float*)d_in[5];
    const float* b3    = (const float*)d_in[6];
    float* out = (float*)d_out;
    short* ws  = (short*)d_ws;   // needs 272*2048 = 557056 bytes

    hipLaunchKernelGGL(prep_weights, dim3(68), dim3(256), 0, stream, W1, W2, W3, ws);
    hipLaunchKernelGGL(sde_mfma_kernel, dim3(BATCHN / 16), dim3(1024), 0, stream,
                       noise, W1, b1, b2, b3, ws, out);
}